// Round 2
// baseline (585.223 us; speedup 1.0000x reference)
//
#include <hip/hip_runtime.h>
#include <hip/hip_bf16.h>

#define NN 100000
#define MM 25000
#define EE 600000

typedef __attribute__((ext_vector_type(8))) short short8;
typedef __attribute__((ext_vector_type(4))) float floatx4;

__device__ __forceinline__ float bl(unsigned int u){ return __uint_as_float(u << 16); }
__device__ __forceinline__ float bh(unsigned int u){ return __uint_as_float(u & 0xffff0000u); }
__device__ __forceinline__ unsigned int packbf2(float a, float b){
    unsigned int ua = __float_as_uint(a), ub = __float_as_uint(b);
    ua = (ua + 0x7fffu + ((ua >> 16) & 1u)) >> 16;
    ub = (ub + 0x7fffu + ((ub >> 16) & 1u)) & 0xffff0000u;
    return ua | ub;
}
__device__ __forceinline__ unsigned short f2bf(float f){
    unsigned int u = __float_as_uint(f);
    return (unsigned short)((u + 0x7fffu + ((u >> 16) & 1u)) >> 16);
}

// ---------------- CSR build ----------------
__global__ void k_hist(const int* __restrict__ nidx, const int* __restrict__ hidx,
                       int* __restrict__ he_cnt, int* __restrict__ n_cnt) {
    int e = blockIdx.x * 256 + threadIdx.x;
    if (e < EE) {
        atomicAdd(&he_cnt[hidx[e]], 1);
        atomicAdd(&n_cnt[nidx[e]], 1);
    }
}

__global__ void k_inv(const int* __restrict__ he_cnt, const int* __restrict__ n_cnt,
                      float* __restrict__ b_inv, float* __restrict__ d_inv) {
    int i = blockIdx.x * 256 + threadIdx.x;
    if (i < MM) { int c = he_cnt[i]; b_inv[i] = c ? 1.0f / (float)c : 0.0f; }
    if (i < NN) { int c = n_cnt[i];  d_inv[i] = c ? 1.0f / (float)c : 0.0f; }
}

__global__ void k_scan_reduce(const int* __restrict__ cnt, int* __restrict__ sums, int n) {
    __shared__ int lds[256];
    int t = threadIdx.x;
    int base = blockIdx.x * 1024 + t * 4;
    int s = 0;
    #pragma unroll
    for (int j = 0; j < 4; j++) { int i = base + j; if (i < n) s += cnt[i]; }
    lds[t] = s; __syncthreads();
    for (int o = 128; o > 0; o >>= 1) { if (t < o) lds[t] += lds[t + o]; __syncthreads(); }
    if (t == 0) sums[blockIdx.x] = lds[0];
}

__global__ void k_scan_top(int* __restrict__ sums, int nb) {
    __shared__ int lds[256];
    int t = threadIdx.x;
    int v = (t < nb) ? sums[t] : 0;
    lds[t] = v; __syncthreads();
    for (int o = 1; o < 256; o <<= 1) {
        int add = (t >= o) ? lds[t - o] : 0;
        __syncthreads();
        lds[t] += add;
        __syncthreads();
    }
    if (t < nb) sums[t] = lds[t] - v;      // exclusive
    if (t == 255) sums[nb] = lds[255];     // total
}

__global__ void k_scan_final(const int* __restrict__ cnt, const int* __restrict__ sums,
                             int* __restrict__ ptr, int n, int nb) {
    __shared__ int lds[256];
    int t = threadIdx.x, b = blockIdx.x;
    int base = b * 1024 + t * 4;
    int v0 = 0, v1 = 0, v2 = 0, v3 = 0;
    if (base + 0 < n) v0 = cnt[base + 0];
    if (base + 1 < n) v1 = cnt[base + 1];
    if (base + 2 < n) v2 = cnt[base + 2];
    if (base + 3 < n) v3 = cnt[base + 3];
    int ts = v0 + v1 + v2 + v3;
    lds[t] = ts; __syncthreads();
    for (int o = 1; o < 256; o <<= 1) {
        int add = (t >= o) ? lds[t - o] : 0;
        __syncthreads();
        lds[t] += add;
        __syncthreads();
    }
    int off = sums[b] + lds[t] - ts;
    if (base + 0 < n) ptr[base + 0] = off;
    if (base + 1 < n) ptr[base + 1] = off + v0;
    if (base + 2 < n) ptr[base + 2] = off + v0 + v1;
    if (base + 3 < n) ptr[base + 3] = off + v0 + v1 + v2;
    if (b == 0 && t == 0) ptr[n] = sums[nb];
}

__global__ void k_fill(const int* __restrict__ nidx, const int* __restrict__ hidx,
                       const int* __restrict__ he_ptr, const int* __restrict__ n_ptr,
                       int* __restrict__ he_fill, int* __restrict__ n_fill,
                       int* __restrict__ he_adj, int* __restrict__ n_adj) {
    int e = blockIdx.x * 256 + threadIdx.x;
    if (e < EE) {
        int h = hidx[e], nd = nidx[e];
        int p = atomicAdd(&he_fill[h], 1);
        he_adj[he_ptr[h] + p] = nd;
        int q = atomicAdd(&n_fill[nd], 1);
        n_adj[n_ptr[nd] + q] = h;
    }
}

// ---------------- weight transpose + f32->bf16 (once, all 3 layers) ----------------
__global__ void k_transw(const float* __restrict__ W1,
                         const float* __restrict__ W2,
                         const float* __restrict__ W3,
                         unsigned short* __restrict__ WT) {
    const float* W = blockIdx.x == 0 ? W1 : (blockIdx.x == 1 ? W2 : W3);
    unsigned short* T = WT + blockIdx.x * 16384;
    for (int i = threadIdx.x; i < 16384; i += 256) {
        int k = i >> 7, c = i & 127;
        T[c * 128 + k] = f2bf(W[k * 128 + c]);
    }
}

// ---------------- gather: hyperedge side  s_e = b_inv * sum x[node] ----------------
// F32IN: xin is float[*][128]; else packed bf16 pairs (uint[*][64]).
template<bool F32IN>
__global__ void k_gather_he(const void* __restrict__ xin,
                            const int* __restrict__ he_ptr, const int* __restrict__ he_adj,
                            const float* __restrict__ b_inv, unsigned int* __restrict__ s) {
    int w = (blockIdx.x * 256 + threadIdx.x) >> 6;
    int lane = threadIdx.x & 63;
    if (w >= MM) return;
    int beg = he_ptr[w], end = he_ptr[w + 1];
    float a0 = 0.f, a1 = 0.f;
    for (int base = beg; base < end; base += 64) {
        int rem = end - base;
        int myidx = (lane < rem) ? he_adj[base + lane] : 0;
        int km = rem < 64 ? rem : 64;
        for (int j = 0; j < km; ++j) {
            int nd = __shfl(myidx, j);
            if (F32IN) {
                float2 v = ((const float2*)xin)[nd * 64 + lane];
                a0 += v.x; a1 += v.y;
            } else {
                unsigned int u = ((const unsigned int*)xin)[nd * 64 + lane];
                a0 += bl(u); a1 += bh(u);
            }
        }
    }
    float sc = b_inv[w];
    s[w * 64 + lane] = packbf2(a0 * sc, a1 * sc);
}

// ---------------- gather: node side  out = elu(d_inv * sum m[e] + b) ----------------
// F32OUT: out is float[*][128]; else packed bf16 pairs.
template<bool F32OUT>
__global__ void k_gather_nd(const unsigned int* __restrict__ mw,
                            const int* __restrict__ n_ptr, const int* __restrict__ n_adj,
                            const float* __restrict__ d_inv, const float* __restrict__ bias,
                            void* __restrict__ out) {
    int w = (blockIdx.x * 256 + threadIdx.x) >> 6;
    int lane = threadIdx.x & 63;
    if (w >= NN) return;
    int beg = n_ptr[w], end = n_ptr[w + 1];
    float a0 = 0.f, a1 = 0.f;
    for (int base = beg; base < end; base += 64) {
        int rem = end - base;
        int myidx = (lane < rem) ? n_adj[base + lane] : 0;
        int km = rem < 64 ? rem : 64;
        for (int j = 0; j < km; ++j) {
            int e = __shfl(myidx, j);
            unsigned int u = mw[e * 64 + lane];
            a0 += bl(u); a1 += bh(u);
        }
    }
    float sc = d_inv[w];
    float2 bb = ((const float2*)bias)[lane];
    a0 = a0 * sc + bb.x;
    a1 = a1 * sc + bb.y;
    a0 = a0 > 0.f ? a0 : __expf(a0) - 1.f;
    a1 = a1 > 0.f ? a1 : __expf(a1) - 1.f;
    if (F32OUT) {
        ((float2*)out)[w * 64 + lane] = make_float2(a0, a1);
    } else {
        ((unsigned int*)out)[w * 64 + lane] = packbf2(a0, a1);
    }
}

// ---------------- GEMM  m[MM,128] = s[MM,128] @ W[128,128]  (WT is W^T, bf16) ----------------
__global__ __launch_bounds__(256) void k_gemm(const unsigned short* __restrict__ A,
                                              const unsigned short* __restrict__ WT,
                                              unsigned short* __restrict__ C) {
    int lane = threadIdx.x & 63;
    int wv = threadIdx.x >> 6;
    int r0 = blockIdx.x * 64 + wv * 16;
    int mm = lane & 15;
    int quad = lane >> 4;
    floatx4 acc[8];
    #pragma unroll
    for (int c = 0; c < 8; c++) acc[c] = (floatx4){0.f, 0.f, 0.f, 0.f};
    int arow = r0 + mm; if (arow >= MM) arow = MM - 1;
    #pragma unroll
    for (int q = 0; q < 4; q++) {
        short8 af = *reinterpret_cast<const short8*>(A + arow * 128 + q * 32 + quad * 8);
        #pragma unroll
        for (int c = 0; c < 8; c++) {
            short8 bf = *reinterpret_cast<const short8*>(WT + (c * 16 + mm) * 128 + q * 32 + quad * 8);
            acc[c] = __builtin_amdgcn_mfma_f32_16x16x32_bf16(af, bf, acc[c], 0, 0, 0);
        }
    }
    #pragma unroll
    for (int c = 0; c < 8; c++) {
        #pragma unroll
        for (int r = 0; r < 4; r++) {
            int row = r0 + quad * 4 + r;
            if (row < MM) {
                C[row * 128 + c * 16 + mm] = f2bf(acc[c][r]);
            }
        }
    }
}

extern "C" void kernel_launch(void* const* d_in, const int* in_sizes, int n_in,
                              void* d_out, int out_size, void* d_ws, size_t ws_size,
                              hipStream_t stream) {
    const float* x  = (const float*)d_in[0];
    const float* W1 = (const float*)d_in[1];
    const float* b1 = (const float*)d_in[2];
    const float* W2 = (const float*)d_in[3];
    const float* b2 = (const float*)d_in[4];
    const float* W3 = (const float*)d_in[5];
    const float* b3 = (const float*)d_in[6];
    const int* nidx = (const int*)d_in[7];
    const int* hidx = (const int*)d_in[8];

    char* ws = (char*)d_ws;
    size_t o = 0;
    auto alloc = [&](size_t b) -> char* { char* p = ws + o; o = (o + b + 255) & ~(size_t)255; return p; };
    int* he_cnt  = (int*)alloc(MM * 4);
    int* n_cnt   = (int*)alloc(NN * 4);
    int* he_fill = (int*)alloc(MM * 4);
    int* n_fill  = (int*)alloc(NN * 4);
    int* he_ptr  = (int*)alloc((MM + 1) * 4);
    int* n_ptr   = (int*)alloc((NN + 1) * 4);
    int* he_sums = (int*)alloc(260 * 4);
    int* n_sums  = (int*)alloc(260 * 4);
    int* he_adj  = (int*)alloc((size_t)EE * 4);
    int* n_adj   = (int*)alloc((size_t)EE * 4);
    float* b_inv = (float*)alloc(MM * 4);
    float* d_inv = (float*)alloc(NN * 4);
    unsigned short* WT   = (unsigned short*)alloc(3 * 128 * 128 * 2);
    unsigned short* sbuf = (unsigned short*)alloc((size_t)MM * 128 * 2);
    unsigned short* mbuf = (unsigned short*)alloc((size_t)MM * 128 * 2);

    // zero the four counter arrays in one memset (they are contiguous in ws)
    size_t zspan = (size_t)((char*)n_fill + NN * 4 - (char*)he_cnt);
    hipMemsetAsync(he_cnt, 0, zspan, stream);

    k_hist<<<(EE + 255) / 256, 256, 0, stream>>>(nidx, hidx, he_cnt, n_cnt);
    k_inv<<<(NN + 255) / 256, 256, 0, stream>>>(he_cnt, n_cnt, b_inv, d_inv);

    int nb_he = (MM + 1023) / 1024;   // 25
    int nb_n  = (NN + 1023) / 1024;   // 98
    k_scan_reduce<<<nb_he, 256, 0, stream>>>(he_cnt, he_sums, MM);
    k_scan_top<<<1, 256, 0, stream>>>(he_sums, nb_he);
    k_scan_final<<<nb_he, 256, 0, stream>>>(he_cnt, he_sums, he_ptr, MM, nb_he);
    k_scan_reduce<<<nb_n, 256, 0, stream>>>(n_cnt, n_sums, NN);
    k_scan_top<<<1, 256, 0, stream>>>(n_sums, nb_n);
    k_scan_final<<<nb_n, 256, 0, stream>>>(n_cnt, n_sums, n_ptr, NN, nb_n);
    k_fill<<<(EE + 255) / 256, 256, 0, stream>>>(nidx, hidx, he_ptr, n_ptr, he_fill, n_fill, he_adj, n_adj);
    k_transw<<<3, 256, 0, stream>>>(W1, W2, W3, WT);

    // bf16 node intermediates live inside d_out's 51.2MB (two 25.6MB halves)
    unsigned short* bufA = (unsigned short*)d_out;                       // layer-0 output
    unsigned short* bufB = bufA + (size_t)NN * 128;                      // layer-1 output
    const int grid_he = MM * 64 / 256;   // 6250
    const int grid_nd = NN * 64 / 256;   // 25000
    const int grid_gm = (MM + 63) / 64;  // 391

    // Layer 0: f32 x -> bf16 A
    k_gather_he<true ><<<grid_he, 256, 0, stream>>>((const void*)x, he_ptr, he_adj, b_inv, (unsigned int*)sbuf);
    k_gemm<<<grid_gm, 256, 0, stream>>>(sbuf, WT, mbuf);
    k_gather_nd<false><<<grid_nd, 256, 0, stream>>>((const unsigned int*)mbuf, n_ptr, n_adj, d_inv, b1, (void*)bufA);

    // Layer 1: bf16 A -> bf16 B
    k_gather_he<false><<<grid_he, 256, 0, stream>>>((const void*)bufA, he_ptr, he_adj, b_inv, (unsigned int*)sbuf);
    k_gemm<<<grid_gm, 256, 0, stream>>>(sbuf, WT + 16384, mbuf);
    k_gather_nd<false><<<grid_nd, 256, 0, stream>>>((const unsigned int*)mbuf, n_ptr, n_adj, d_inv, b2, (void*)bufB);

    // Layer 2: bf16 B -> f32 d_out
    k_gather_he<false><<<grid_he, 256, 0, stream>>>((const void*)bufB, he_ptr, he_adj, b_inv, (unsigned int*)sbuf);
    k_gemm<<<grid_gm, 256, 0, stream>>>(sbuf, WT + 32768, mbuf);
    k_gather_nd<true ><<<grid_nd, 256, 0, stream>>>((const unsigned int*)mbuf, n_ptr, n_adj, d_inv, b3, d_out);
}

// Round 3
// 483.269 us; speedup vs baseline: 1.2110x; 1.2110x over previous
//
#include <hip/hip_runtime.h>

#define NN 100000
#define MM 25000
#define EE 600000
#define TT (MM + NN)

typedef __attribute__((ext_vector_type(8))) short short8;
typedef __attribute__((ext_vector_type(4))) float floatx4;

__device__ __forceinline__ float bl(unsigned int u){ return __uint_as_float(u << 16); }
__device__ __forceinline__ float bh(unsigned int u){ return __uint_as_float(u & 0xffff0000u); }
__device__ __forceinline__ unsigned int packbf2(float a, float b){
    unsigned int ua = __float_as_uint(a), ub = __float_as_uint(b);
    ua = (ua + 0x7fffu + ((ua >> 16) & 1u)) >> 16;
    ub = (ub + 0x7fffu + ((ub >> 16) & 1u)) & 0xffff0000u;
    return ua | ub;
}
__device__ __forceinline__ unsigned short f2bf(float f){
    unsigned int u = __float_as_uint(f);
    return (unsigned short)((u + 0x7fffu + ((u >> 16) & 1u)) >> 16);
}

// ---------------- x f32 -> bf16 (packed pairs) ----------------
__global__ void k_cvt(const float* __restrict__ x, unsigned int* __restrict__ xb) {
    int t = blockIdx.x * 256 + threadIdx.x;      // each converts 4 floats
    if (t >= NN * 32) return;
    float4 v = ((const float4*)x)[t];
    uint2 o; o.x = packbf2(v.x, v.y); o.y = packbf2(v.z, v.w);
    ((uint2*)xb)[t] = o;
}

// ---------------- CSR build (unified: [0,MM) = hyperedges, [MM,TT) = nodes) ----------------
__global__ void k_hist(const int* __restrict__ nidx, const int* __restrict__ hidx,
                       int* __restrict__ cnt) {
    int e = blockIdx.x * 256 + threadIdx.x;
    if (e < EE) {
        atomicAdd(&cnt[hidx[e]], 1);
        atomicAdd(&cnt[MM + nidx[e]], 1);
    }
}

__global__ void k_scan_reduce(const int* __restrict__ cnt, int* __restrict__ sums, int n) {
    __shared__ int lds[256];
    int t = threadIdx.x;
    int base = blockIdx.x * 1024 + t * 4;
    int s = 0;
    #pragma unroll
    for (int j = 0; j < 4; j++) { int i = base + j; if (i < n) s += cnt[i]; }
    lds[t] = s; __syncthreads();
    for (int o = 128; o > 0; o >>= 1) { if (t < o) lds[t] += lds[t + o]; __syncthreads(); }
    if (t == 0) sums[blockIdx.x] = lds[0];
}

__global__ void k_scan_top(int* __restrict__ sums, int nb) {
    __shared__ int lds[256];
    int t = threadIdx.x;
    int v = (t < nb) ? sums[t] : 0;
    lds[t] = v; __syncthreads();
    for (int o = 1; o < 256; o <<= 1) {
        int add = (t >= o) ? lds[t - o] : 0;
        __syncthreads();
        lds[t] += add;
        __syncthreads();
    }
    if (t < nb) sums[t] = lds[t] - v;      // exclusive
    if (t == 255) sums[nb] = lds[255];     // total
}

// scan finalize + inverse-degree computation fused
__global__ void k_scan_final(const int* __restrict__ cnt, const int* __restrict__ sums,
                             int* __restrict__ ptr, float* __restrict__ inv, int n, int nb) {
    __shared__ int lds[256];
    int t = threadIdx.x, b = blockIdx.x;
    int base = b * 1024 + t * 4;
    int v0 = 0, v1 = 0, v2 = 0, v3 = 0;
    if (base + 0 < n) v0 = cnt[base + 0];
    if (base + 1 < n) v1 = cnt[base + 1];
    if (base + 2 < n) v2 = cnt[base + 2];
    if (base + 3 < n) v3 = cnt[base + 3];
    int ts = v0 + v1 + v2 + v3;
    lds[t] = ts; __syncthreads();
    for (int o = 1; o < 256; o <<= 1) {
        int add = (t >= o) ? lds[t - o] : 0;
        __syncthreads();
        lds[t] += add;
        __syncthreads();
    }
    int off = sums[b] + lds[t] - ts;
    if (base + 0 < n) { ptr[base + 0] = off;                 inv[base + 0] = v0 ? 1.f / (float)v0 : 0.f; }
    if (base + 1 < n) { ptr[base + 1] = off + v0;            inv[base + 1] = v1 ? 1.f / (float)v1 : 0.f; }
    if (base + 2 < n) { ptr[base + 2] = off + v0 + v1;       inv[base + 2] = v2 ? 1.f / (float)v2 : 0.f; }
    if (base + 3 < n) { ptr[base + 3] = off + v0 + v1 + v2;  inv[base + 3] = v3 ? 1.f / (float)v3 : 0.f; }
    if (b == 0 && t == 0) ptr[n] = sums[nb];
}

__global__ void k_fill(const int* __restrict__ nidx, const int* __restrict__ hidx,
                       const int* __restrict__ ptr, int* __restrict__ fill,
                       int* __restrict__ adj) {
    int e = blockIdx.x * 256 + threadIdx.x;
    if (e < EE) {
        int h = hidx[e], nd = nidx[e];
        int p = atomicAdd(&fill[h], 1);
        adj[ptr[h] + p] = nd;
        int q = atomicAdd(&fill[MM + nd], 1);
        adj[ptr[MM + nd] + q] = h;
    }
}

// ---------------- weight transpose + f32->bf16 (once, all 3 layers) ----------------
__global__ void k_transw(const float* __restrict__ W1,
                         const float* __restrict__ W2,
                         const float* __restrict__ W3,
                         unsigned short* __restrict__ WT) {
    const float* W = blockIdx.x == 0 ? W1 : (blockIdx.x == 1 ? W2 : W3);
    unsigned short* T = WT + blockIdx.x * 16384;
    for (int i = threadIdx.x; i < 16384; i += 256) {
        int k = i >> 7, c = i & 127;
        T[c * 128 + k] = f2bf(W[k * 128 + c]);
    }
}

// ---------------- gather core: 4 rows in flight (one per 16-lane quad) ----------------
// X: rows of 64 uints (128 bf16). a[8]: features 8*ql .. 8*ql+7 (lo/hi pairs).
__device__ __forceinline__ void gather_acc(const unsigned int* __restrict__ X,
                                           const int* __restrict__ ptrb, const int* __restrict__ adj,
                                           int w, int lane, int quad, int ql, float* a) {
    int beg = ptrb[w], end = ptrb[w + 1];
    for (int base = beg; base < end; base += 64) {
        int rem = end - base;
        int km = rem < 64 ? rem : 64;
        int myidx = adj[base + (lane < km ? lane : km - 1)];
        for (int j = 0; j < km; j += 4) {
            int r = j + quad;
            int rr = r < km ? r : km - 1;
            int nd = __shfl(myidx, rr);
            uint4 v = *((const uint4*)(X + (unsigned)nd * 64u) + ql);
            if (r < km) {
                a[0] += bl(v.x); a[1] += bh(v.x);
                a[2] += bl(v.y); a[3] += bh(v.y);
                a[4] += bl(v.z); a[5] += bh(v.z);
                a[6] += bl(v.w); a[7] += bh(v.w);
            }
        }
    }
    #pragma unroll
    for (int i = 0; i < 8; i++) {
        a[i] += __shfl_xor(a[i], 16);
        a[i] += __shfl_xor(a[i], 32);
    }
}

// ---------------- gather: hyperedge side  s_e = b_inv * sum x[node] ----------------
__global__ __launch_bounds__(256) void k_gather_he(const unsigned int* __restrict__ X,
        const int* __restrict__ ptr, const int* __restrict__ adj,
        const float* __restrict__ b_inv, unsigned int* __restrict__ s) {
    int w = (blockIdx.x * 256 + threadIdx.x) >> 6;   // grid exact: MM waves
    int lane = threadIdx.x & 63, quad = lane >> 4, ql = lane & 15;
    float a[8] = {0.f,0.f,0.f,0.f,0.f,0.f,0.f,0.f};
    gather_acc(X, ptr, adj, w, lane, quad, ql, a);
    float sc = b_inv[w];
    if (quad == 0) {
        uint4 o;
        o.x = packbf2(a[0] * sc, a[1] * sc);
        o.y = packbf2(a[2] * sc, a[3] * sc);
        o.z = packbf2(a[4] * sc, a[5] * sc);
        o.w = packbf2(a[6] * sc, a[7] * sc);
        ((uint4*)(s + (unsigned)w * 64u))[ql] = o;
    }
}

// ---------------- gather: node side  out = elu(d_inv * sum m[e] + b) ----------------
template<bool F32OUT>
__global__ __launch_bounds__(256) void k_gather_nd(const unsigned int* __restrict__ X,
        const int* __restrict__ ptr, const int* __restrict__ adj,
        const float* __restrict__ d_inv, const float* __restrict__ bias, void* __restrict__ out) {
    int w = (blockIdx.x * 256 + threadIdx.x) >> 6;   // grid exact: NN waves
    int lane = threadIdx.x & 63, quad = lane >> 4, ql = lane & 15;
    float a[8] = {0.f,0.f,0.f,0.f,0.f,0.f,0.f,0.f};
    gather_acc(X, ptr, adj, w, lane, quad, ql, a);
    float sc = d_inv[w];
    const float4* b4 = (const float4*)bias;
    float4 bA = b4[ql * 2], bB = b4[ql * 2 + 1];
    float f[8];
    f[0] = a[0] * sc + bA.x; f[1] = a[1] * sc + bA.y;
    f[2] = a[2] * sc + bA.z; f[3] = a[3] * sc + bA.w;
    f[4] = a[4] * sc + bB.x; f[5] = a[5] * sc + bB.y;
    f[6] = a[6] * sc + bB.z; f[7] = a[7] * sc + bB.w;
    #pragma unroll
    for (int i = 0; i < 8; i++) f[i] = f[i] > 0.f ? f[i] : __expf(f[i]) - 1.f;
    if (F32OUT) {
        float* o = (float*)out + (unsigned)w * 128u;
        if (quad == 0) ((float4*)o)[ql * 2]     = make_float4(f[0], f[1], f[2], f[3]);
        if (quad == 1) ((float4*)o)[ql * 2 + 1] = make_float4(f[4], f[5], f[6], f[7]);
    } else {
        if (quad == 0) {
            uint4 o4;
            o4.x = packbf2(f[0], f[1]); o4.y = packbf2(f[2], f[3]);
            o4.z = packbf2(f[4], f[5]); o4.w = packbf2(f[6], f[7]);
            ((uint4*)((unsigned int*)out + (unsigned)w * 64u))[ql] = o4;
        }
    }
}

// ---------------- GEMM  m[MM,128] = s[MM,128] @ W[128,128]  (WT is W^T, bf16) ----------------
__global__ __launch_bounds__(256) void k_gemm(const unsigned short* __restrict__ A,
                                              const unsigned short* __restrict__ WT,
                                              unsigned short* __restrict__ C) {
    int lane = threadIdx.x & 63;
    int wv = threadIdx.x >> 6;
    int r0 = blockIdx.x * 64 + wv * 16;
    int mm = lane & 15;
    int quad = lane >> 4;
    floatx4 acc[8];
    #pragma unroll
    for (int c = 0; c < 8; c++) acc[c] = (floatx4){0.f, 0.f, 0.f, 0.f};
    int arow = r0 + mm; if (arow >= MM) arow = MM - 1;
    #pragma unroll
    for (int q = 0; q < 4; q++) {
        short8 af = *reinterpret_cast<const short8*>(A + arow * 128 + q * 32 + quad * 8);
        #pragma unroll
        for (int c = 0; c < 8; c++) {
            short8 bf = *reinterpret_cast<const short8*>(WT + (c * 16 + mm) * 128 + q * 32 + quad * 8);
            acc[c] = __builtin_amdgcn_mfma_f32_16x16x32_bf16(af, bf, acc[c], 0, 0, 0);
        }
    }
    #pragma unroll
    for (int c = 0; c < 8; c++) {
        #pragma unroll
        for (int r = 0; r < 4; r++) {
            int row = r0 + quad * 4 + r;
            if (row < MM) {
                C[row * 128 + c * 16 + mm] = f2bf(acc[c][r]);
            }
        }
    }
}

extern "C" void kernel_launch(void* const* d_in, const int* in_sizes, int n_in,
                              void* d_out, int out_size, void* d_ws, size_t ws_size,
                              hipStream_t stream) {
    const float* x  = (const float*)d_in[0];
    const float* W1 = (const float*)d_in[1];
    const float* b1 = (const float*)d_in[2];
    const float* W2 = (const float*)d_in[3];
    const float* b2 = (const float*)d_in[4];
    const float* W3 = (const float*)d_in[5];
    const float* b3 = (const float*)d_in[6];
    const int* nidx = (const int*)d_in[7];
    const int* hidx = (const int*)d_in[8];

    char* ws = (char*)d_ws;
    size_t o = 0;
    auto alloc = [&](size_t b) -> char* { char* p = ws + o; o = (o + b + 255) & ~(size_t)255; return p; };
    int*   cnt  = (int*)alloc(TT * 4);
    int*   fill = (int*)alloc(TT * 4);             // contiguous with cnt for single memset
    int*   ptr  = (int*)alloc((TT + 1) * 4);
    int*   sums = (int*)alloc(260 * 4);
    int*   adj  = (int*)alloc((size_t)2 * EE * 4); // [0,EE): he_adj ; [EE,2EE): n_adj
    float* invq = (float*)alloc(TT * 4);           // [0,MM): b_inv ; [MM,TT): d_inv
    unsigned short* WT   = (unsigned short*)alloc(3 * 128 * 128 * 2);
    unsigned short* sbuf = (unsigned short*)alloc((size_t)MM * 128 * 2);
    unsigned short* mbuf = (unsigned short*)alloc((size_t)MM * 128 * 2);

    // zero cnt+fill in one memset (contiguous span)
    size_t zspan = (size_t)((char*)fill + TT * 4 - (char*)cnt);
    hipMemsetAsync(cnt, 0, zspan, stream);

    // d_out (51.2MB) hosts: xb (bf16 x, first half, dead after layer-0 he-gather),
    // bufA (layer-0 out, first half), bufB (layer-1 out, second half), final f32 (all).
    unsigned int* xb   = (unsigned int*)d_out;
    unsigned int* bufA = (unsigned int*)d_out;
    unsigned int* bufB = (unsigned int*)d_out + (size_t)NN * 64;

    k_cvt<<<(NN * 32 + 255) / 256, 256, 0, stream>>>(x, xb);
    k_hist<<<(EE + 255) / 256, 256, 0, stream>>>(nidx, hidx, cnt);

    int nb = (TT + 1023) / 1024;   // 123
    k_scan_reduce<<<nb, 256, 0, stream>>>(cnt, sums, TT);
    k_scan_top<<<1, 256, 0, stream>>>(sums, nb);
    k_scan_final<<<nb, 256, 0, stream>>>(cnt, sums, ptr, invq, TT, nb);
    k_fill<<<(EE + 255) / 256, 256, 0, stream>>>(nidx, hidx, ptr, fill, adj);
    k_transw<<<3, 256, 0, stream>>>(W1, W2, W3, WT);

    const float* b_inv = invq;
    const float* d_inv = invq + MM;
    const int* nptr = ptr + MM;
    const int grid_he = MM * 64 / 256;   // 6250 (exact)
    const int grid_nd = NN * 64 / 256;   // 25000 (exact)
    const int grid_gm = (MM + 63) / 64;  // 391

    // Layer 0
    k_gather_he<<<grid_he, 256, 0, stream>>>(xb, ptr, adj, b_inv, (unsigned int*)sbuf);
    k_gemm<<<grid_gm, 256, 0, stream>>>(sbuf, WT, mbuf);
    k_gather_nd<false><<<grid_nd, 256, 0, stream>>>((const unsigned int*)mbuf, nptr, adj, d_inv, b1, (void*)bufA);
    // Layer 1
    k_gather_he<<<grid_he, 256, 0, stream>>>(bufA, ptr, adj, b_inv, (unsigned int*)sbuf);
    k_gemm<<<grid_gm, 256, 0, stream>>>(sbuf, WT + 16384, mbuf);
    k_gather_nd<false><<<grid_nd, 256, 0, stream>>>((const unsigned int*)mbuf, nptr, adj, d_inv, b2, (void*)bufB);
    // Layer 2
    k_gather_he<<<grid_he, 256, 0, stream>>>(bufB, ptr, adj, b_inv, (unsigned int*)sbuf);
    k_gemm<<<grid_gm, 256, 0, stream>>>(sbuf, WT + 32768, mbuf);
    k_gather_nd<true ><<<grid_nd, 256, 0, stream>>>((const unsigned int*)mbuf, nptr, adj, d_inv, b3, d_out);
}

// Round 4
// 465.538 us; speedup vs baseline: 1.2571x; 1.0381x over previous
//
#include <hip/hip_runtime.h>

#define NN 100000
#define MM 25000
#define EE 600000
#define TT (MM + NN)

#define CVT_BLOCKS 12500            // NN*32/256 exact
#define HIST_BLOCKS ((EE + 255) / 256)

typedef __attribute__((ext_vector_type(8))) short short8;
typedef __attribute__((ext_vector_type(4))) float floatx4;

__device__ __forceinline__ float bl(unsigned int u){ return __uint_as_float(u << 16); }
__device__ __forceinline__ float bh(unsigned int u){ return __uint_as_float(u & 0xffff0000u); }
__device__ __forceinline__ unsigned int packbf2(float a, float b){
    unsigned int ua = __float_as_uint(a), ub = __float_as_uint(b);
    ua = (ua + 0x7fffu + ((ua >> 16) & 1u)) >> 16;
    ub = (ub + 0x7fffu + ((ub >> 16) & 1u)) & 0xffff0000u;
    return ua | ub;
}
__device__ __forceinline__ unsigned short f2bf(float f){
    unsigned int u = __float_as_uint(f);
    return (unsigned short)((u + 0x7fffu + ((u >> 16) & 1u)) >> 16);
}

// ---------------- fused preamble: x->bf16 | degree histogram | weight transpose ----------------
__global__ void k_setup(const float* __restrict__ x, unsigned int* __restrict__ xb,
                        const int* __restrict__ nidx, const int* __restrict__ hidx,
                        int* __restrict__ cnt,
                        const float* __restrict__ W1, const float* __restrict__ W2,
                        const float* __restrict__ W3, unsigned short* __restrict__ WT) {
    int b = blockIdx.x;
    if (b < CVT_BLOCKS) {
        int t = b * 256 + threadIdx.x;
        float4 v = ((const float4*)x)[t];
        uint2 o; o.x = packbf2(v.x, v.y); o.y = packbf2(v.z, v.w);
        ((uint2*)xb)[t] = o;
    } else if (b < CVT_BLOCKS + HIST_BLOCKS) {
        int e = (b - CVT_BLOCKS) * 256 + threadIdx.x;
        if (e < EE) {
            atomicAdd(&cnt[hidx[e]], 1);
            atomicAdd(&cnt[MM + nidx[e]], 1);
        }
    } else {
        int l = b - CVT_BLOCKS - HIST_BLOCKS;
        const float* W = l == 0 ? W1 : (l == 1 ? W2 : W3);
        unsigned short* T = WT + l * 16384;
        for (int i = threadIdx.x; i < 16384; i += 256) {
            int k = i >> 7, c = i & 127;
            T[c * 128 + k] = f2bf(W[k * 128 + c]);
        }
    }
}

// ---------------- scan ----------------
__global__ void k_scan_reduce(const int* __restrict__ cnt, int* __restrict__ sums, int n) {
    __shared__ int lds[256];
    int t = threadIdx.x;
    int base = blockIdx.x * 1024 + t * 4;
    int s = 0;
    #pragma unroll
    for (int j = 0; j < 4; j++) { int i = base + j; if (i < n) s += cnt[i]; }
    lds[t] = s; __syncthreads();
    for (int o = 128; o > 0; o >>= 1) { if (t < o) lds[t] += lds[t + o]; __syncthreads(); }
    if (t == 0) sums[blockIdx.x] = lds[0];
}

__global__ void k_scan_top(int* __restrict__ sums, int nb) {
    __shared__ int lds[256];
    int t = threadIdx.x;
    int v = (t < nb) ? sums[t] : 0;
    lds[t] = v; __syncthreads();
    for (int o = 1; o < 256; o <<= 1) {
        int add = (t >= o) ? lds[t - o] : 0;
        __syncthreads();
        lds[t] += add;
        __syncthreads();
    }
    if (t < nb) sums[t] = lds[t] - v;
    if (t == 255) sums[nb] = lds[255];
}

__global__ void k_scan_final(const int* __restrict__ cnt, const int* __restrict__ sums,
                             int* __restrict__ ptr, float* __restrict__ inv, int n, int nb) {
    __shared__ int lds[256];
    int t = threadIdx.x, b = blockIdx.x;
    int base = b * 1024 + t * 4;
    int v0 = 0, v1 = 0, v2 = 0, v3 = 0;
    if (base + 0 < n) v0 = cnt[base + 0];
    if (base + 1 < n) v1 = cnt[base + 1];
    if (base + 2 < n) v2 = cnt[base + 2];
    if (base + 3 < n) v3 = cnt[base + 3];
    int ts = v0 + v1 + v2 + v3;
    lds[t] = ts; __syncthreads();
    for (int o = 1; o < 256; o <<= 1) {
        int add = (t >= o) ? lds[t - o] : 0;
        __syncthreads();
        lds[t] += add;
        __syncthreads();
    }
    int off = sums[b] + lds[t] - ts;
    if (base + 0 < n) { ptr[base + 0] = off;                 inv[base + 0] = v0 ? 1.f / (float)v0 : 0.f; }
    if (base + 1 < n) { ptr[base + 1] = off + v0;            inv[base + 1] = v1 ? 1.f / (float)v1 : 0.f; }
    if (base + 2 < n) { ptr[base + 2] = off + v0 + v1;       inv[base + 2] = v2 ? 1.f / (float)v2 : 0.f; }
    if (base + 3 < n) { ptr[base + 3] = off + v0 + v1 + v2;  inv[base + 3] = v3 ? 1.f / (float)v3 : 0.f; }
    if (b == 0 && t == 0) ptr[n] = sums[nb];
}

__global__ void k_fill(const int* __restrict__ nidx, const int* __restrict__ hidx,
                       const int* __restrict__ ptr, int* __restrict__ fill,
                       int* __restrict__ adj) {
    int e = blockIdx.x * 256 + threadIdx.x;
    if (e < EE) {
        int h = hidx[e], nd = nidx[e];
        int p = atomicAdd(&fill[h], 1);
        adj[ptr[h] + p] = nd;
        int q = atomicAdd(&fill[MM + nd], 1);
        adj[ptr[MM + nd] + q] = h;
    }
}

// ---------------- gather core: 8 rows in flight (2 per 16-lane quad), exec-masked tails ----------
__device__ __forceinline__ void gather_acc(const unsigned int* __restrict__ X,
                                           const int* __restrict__ ptrb, const int* __restrict__ adj,
                                           int w, int lane, int quad, int ql, float* a) {
    int beg = ptrb[w], end = ptrb[w + 1];
    for (int base = beg; base < end; base += 64) {
        int rem = end - base;
        int km = rem < 64 ? rem : 64;
        int myidx = adj[base + (lane < km ? lane : 0)];
        for (int j = 0; j < km; j += 8) {
            int r0 = j + quad, r1 = j + quad + 4;
            int s0 = __shfl(myidx, r0 < km ? r0 : 0);
            int s1 = __shfl(myidx, r1 < km ? r1 : 0);
            uint4 v0 = make_uint4(0u, 0u, 0u, 0u), v1 = make_uint4(0u, 0u, 0u, 0u);
            if (r0 < km) v0 = *((const uint4*)(X + (unsigned)s0 * 64u) + ql);
            if (r1 < km) v1 = *((const uint4*)(X + (unsigned)s1 * 64u) + ql);
            a[0] += bl(v0.x); a[1] += bh(v0.x);
            a[2] += bl(v0.y); a[3] += bh(v0.y);
            a[4] += bl(v0.z); a[5] += bh(v0.z);
            a[6] += bl(v0.w); a[7] += bh(v0.w);
            a[0] += bl(v1.x); a[1] += bh(v1.x);
            a[2] += bl(v1.y); a[3] += bh(v1.y);
            a[4] += bl(v1.z); a[5] += bh(v1.z);
            a[6] += bl(v1.w); a[7] += bh(v1.w);
        }
    }
    #pragma unroll
    for (int i = 0; i < 8; i++) {
        a[i] += __shfl_xor(a[i], 16);
        a[i] += __shfl_xor(a[i], 32);
    }
}

// ---------------- gather: hyperedge side ----------------
__global__ __launch_bounds__(256) void k_gather_he(const unsigned int* __restrict__ X,
        const int* __restrict__ ptr, const int* __restrict__ adj,
        const float* __restrict__ b_inv, unsigned int* __restrict__ s) {
    int w = (blockIdx.x * 256 + threadIdx.x) >> 6;
    int lane = threadIdx.x & 63, quad = lane >> 4, ql = lane & 15;
    float a[8] = {0.f,0.f,0.f,0.f,0.f,0.f,0.f,0.f};
    gather_acc(X, ptr, adj, w, lane, quad, ql, a);
    float sc = b_inv[w];
    if (quad == 0) {
        uint4 o;
        o.x = packbf2(a[0] * sc, a[1] * sc);
        o.y = packbf2(a[2] * sc, a[3] * sc);
        o.z = packbf2(a[4] * sc, a[5] * sc);
        o.w = packbf2(a[6] * sc, a[7] * sc);
        ((uint4*)(s + (unsigned)w * 64u))[ql] = o;
    }
}

// ---------------- gather: node side ----------------
template<bool F32OUT>
__global__ __launch_bounds__(256) void k_gather_nd(const unsigned int* __restrict__ X,
        const int* __restrict__ ptr, const int* __restrict__ adj,
        const float* __restrict__ d_inv, const float* __restrict__ bias, void* __restrict__ out) {
    int w = (blockIdx.x * 256 + threadIdx.x) >> 6;
    int lane = threadIdx.x & 63, quad = lane >> 4, ql = lane & 15;
    float a[8] = {0.f,0.f,0.f,0.f,0.f,0.f,0.f,0.f};
    gather_acc(X, ptr, adj, w, lane, quad, ql, a);
    float sc = d_inv[w];
    const float4* b4 = (const float4*)bias;
    float4 bA = b4[ql * 2], bB = b4[ql * 2 + 1];
    float f[8];
    f[0] = a[0] * sc + bA.x; f[1] = a[1] * sc + bA.y;
    f[2] = a[2] * sc + bA.z; f[3] = a[3] * sc + bA.w;
    f[4] = a[4] * sc + bB.x; f[5] = a[5] * sc + bB.y;
    f[6] = a[6] * sc + bB.z; f[7] = a[7] * sc + bB.w;
    #pragma unroll
    for (int i = 0; i < 8; i++) f[i] = f[i] > 0.f ? f[i] : __expf(f[i]) - 1.f;
    if (F32OUT) {
        float* o = (float*)out + (unsigned)w * 128u;
        if (quad == 0) ((float4*)o)[ql * 2]     = make_float4(f[0], f[1], f[2], f[3]);
        if (quad == 1) ((float4*)o)[ql * 2 + 1] = make_float4(f[4], f[5], f[6], f[7]);
    } else {
        if (quad == 0) {
            uint4 o4;
            o4.x = packbf2(f[0], f[1]); o4.y = packbf2(f[2], f[3]);
            o4.z = packbf2(f[4], f[5]); o4.w = packbf2(f[6], f[7]);
            ((uint4*)((unsigned int*)out + (unsigned)w * 64u))[ql] = o4;
        }
    }
}

// ---------------- GEMM  m[MM,128] = s[MM,128] @ W  (WT is W^T, bf16) ----------------
__global__ __launch_bounds__(256) void k_gemm(const unsigned short* __restrict__ A,
                                              const unsigned short* __restrict__ WT,
                                              unsigned short* __restrict__ C) {
    int lane = threadIdx.x & 63;
    int wv = threadIdx.x >> 6;
    int r0 = blockIdx.x * 64 + wv * 16;
    int mm = lane & 15;
    int quad = lane >> 4;
    floatx4 acc[8];
    #pragma unroll
    for (int c = 0; c < 8; c++) acc[c] = (floatx4){0.f, 0.f, 0.f, 0.f};
    int arow = r0 + mm; if (arow >= MM) arow = MM - 1;
    #pragma unroll
    for (int q = 0; q < 4; q++) {
        short8 af = *reinterpret_cast<const short8*>(A + arow * 128 + q * 32 + quad * 8);
        #pragma unroll
        for (int c = 0; c < 8; c++) {
            short8 bf = *reinterpret_cast<const short8*>(WT + (c * 16 + mm) * 128 + q * 32 + quad * 8);
            acc[c] = __builtin_amdgcn_mfma_f32_16x16x32_bf16(af, bf, acc[c], 0, 0, 0);
        }
    }
    #pragma unroll
    for (int c = 0; c < 8; c++) {
        #pragma unroll
        for (int r = 0; r < 4; r++) {
            int row = r0 + quad * 4 + r;
            if (row < MM) C[row * 128 + c * 16 + mm] = f2bf(acc[c][r]);
        }
    }
}

extern "C" void kernel_launch(void* const* d_in, const int* in_sizes, int n_in,
                              void* d_out, int out_size, void* d_ws, size_t ws_size,
                              hipStream_t stream) {
    const float* x  = (const float*)d_in[0];
    const float* W1 = (const float*)d_in[1];
    const float* b1 = (const float*)d_in[2];
    const float* W2 = (const float*)d_in[3];
    const float* b2 = (const float*)d_in[4];
    const float* W3 = (const float*)d_in[5];
    const float* b3 = (const float*)d_in[6];
    const int* nidx = (const int*)d_in[7];
    const int* hidx = (const int*)d_in[8];

    char* ws = (char*)d_ws;
    size_t o = 0;
    auto alloc = [&](size_t b) -> char* { char* p = ws + o; o = (o + b + 255) & ~(size_t)255; return p; };
    int*   cnt  = (int*)alloc(TT * 4);
    int*   fill = (int*)alloc(TT * 4);             // contiguous with cnt for single memset
    int*   ptr  = (int*)alloc((TT + 1) * 4);
    int*   sums = (int*)alloc(260 * 4);
    int*   adj  = (int*)alloc((size_t)2 * EE * 4);
    float* invq = (float*)alloc(TT * 4);           // [0,MM): b_inv ; [MM,TT): d_inv
    unsigned short* WT   = (unsigned short*)alloc(3 * 128 * 128 * 2);
    unsigned short* sbuf = (unsigned short*)alloc((size_t)MM * 128 * 2);
    unsigned short* mbuf = (unsigned short*)alloc((size_t)MM * 128 * 2);

    size_t zspan = (size_t)((char*)fill + TT * 4 - (char*)cnt);
    hipMemsetAsync(cnt, 0, zspan, stream);

    // d_out hosts: xb/bufA (first half), bufB (second half), final f32 (all)
    unsigned int* xb   = (unsigned int*)d_out;
    unsigned int* bufA = (unsigned int*)d_out;
    unsigned int* bufB = (unsigned int*)d_out + (size_t)NN * 64;

    k_setup<<<CVT_BLOCKS + HIST_BLOCKS + 3, 256, 0, stream>>>(x, xb, nidx, hidx, cnt, W1, W2, W3, WT);

    int nb = (TT + 1023) / 1024;   // 123
    k_scan_reduce<<<nb, 256, 0, stream>>>(cnt, sums, TT);
    k_scan_top<<<1, 256, 0, stream>>>(sums, nb);
    k_scan_final<<<nb, 256, 0, stream>>>(cnt, sums, ptr, invq, TT, nb);
    k_fill<<<(EE + 255) / 256, 256, 0, stream>>>(nidx, hidx, ptr, fill, adj);

    const float* b_inv = invq;
    const float* d_inv = invq + MM;
    const int* nptr = ptr + MM;
    const int grid_he = MM * 64 / 256;
    const int grid_nd = NN * 64 / 256;
    const int grid_gm = (MM + 63) / 64;

    // Layer 0
    k_gather_he<<<grid_he, 256, 0, stream>>>(xb, ptr, adj, b_inv, (unsigned int*)sbuf);
    k_gemm<<<grid_gm, 256, 0, stream>>>(sbuf, WT, mbuf);
    k_gather_nd<false><<<grid_nd, 256, 0, stream>>>((const unsigned int*)mbuf, nptr, adj, d_inv, b1, (void*)bufA);
    // Layer 1
    k_gather_he<<<grid_he, 256, 0, stream>>>(bufA, ptr, adj, b_inv, (unsigned int*)sbuf);
    k_gemm<<<grid_gm, 256, 0, stream>>>(sbuf, WT + 16384, mbuf);
    k_gather_nd<false><<<grid_nd, 256, 0, stream>>>((const unsigned int*)mbuf, nptr, adj, d_inv, b2, (void*)bufB);
    // Layer 2
    k_gather_he<<<grid_he, 256, 0, stream>>>(bufB, ptr, adj, b_inv, (unsigned int*)sbuf);
    k_gemm<<<grid_gm, 256, 0, stream>>>(sbuf, WT + 32768, mbuf);
    k_gather_nd<true ><<<grid_nd, 256, 0, stream>>>((const unsigned int*)mbuf, nptr, adj, d_inv, b3, d_out);
}

// Round 5
// 364.889 us; speedup vs baseline: 1.6038x; 1.2758x over previous
//
#include <hip/hip_runtime.h>

#define NN 100000
#define MM 25000
#define EE 600000
#define TT (MM + NN)

#define CVT_BLOCKS 12500              // NN*128/4/256 exact
#define NB 782                        // 391 he buckets (h>>6) + 391 nd buckets (n>>8)
#define TILE_E 4096
#define GA ((EE + TILE_E - 1) / TILE_E)   // 147

typedef __attribute__((ext_vector_type(8))) short short8;
typedef __attribute__((ext_vector_type(4))) float floatx4;

__device__ __forceinline__ float bl(unsigned int u){ return __uint_as_float(u << 16); }
__device__ __forceinline__ float bh(unsigned int u){ return __uint_as_float(u & 0xffff0000u); }
__device__ __forceinline__ unsigned int packbf2(float a, float b){
    unsigned int ua = __float_as_uint(a), ub = __float_as_uint(b);
    ua = (ua + 0x7fffu + ((ua >> 16) & 1u)) >> 16;
    ub = (ub + 0x7fffu + ((ub >> 16) & 1u)) & 0xffff0000u;
    return ua | ub;
}
__device__ __forceinline__ unsigned short f2bf(float f){
    unsigned int u = __float_as_uint(f);
    return (unsigned short)((u + 0x7fffu + ((u >> 16) & 1u)) >> 16);
}
__device__ __forceinline__ void acc8(float* a, uint4 v){
    a[0] += bl(v.x); a[1] += bh(v.x);
    a[2] += bl(v.y); a[3] += bh(v.y);
    a[4] += bl(v.z); a[5] += bh(v.z);
    a[6] += bl(v.w); a[7] += bh(v.w);
}

// ---------------- preamble: x->bf16 | weight transpose ----------------
__global__ void k_setup(const float* __restrict__ x, unsigned int* __restrict__ xb,
                        const float* __restrict__ W1, const float* __restrict__ W2,
                        const float* __restrict__ W3, unsigned short* __restrict__ WT) {
    int b = blockIdx.x;
    if (b < CVT_BLOCKS) {
        int t = b * 256 + threadIdx.x;
        float4 v = ((const float4*)x)[t];
        uint2 o; o.x = packbf2(v.x, v.y); o.y = packbf2(v.z, v.w);
        ((uint2*)xb)[t] = o;
    } else {
        int l = b - CVT_BLOCKS;
        const float* W = l == 0 ? W1 : (l == 1 ? W2 : W3);
        unsigned short* T = WT + l * 16384;
        for (int i = threadIdx.x; i < 16384; i += 256) {
            int k = i >> 7, c = i & 127;
            T[c * 128 + k] = f2bf(W[k * 128 + c]);
        }
    }
}

// ---------------- CSR build, pass A1: per-block bucket histogram ----------------
__global__ __launch_bounds__(256) void k_histA(const int* __restrict__ nidx, const int* __restrict__ hidx,
                                               int* __restrict__ counts) {
    __shared__ int h[NB];
    int t = threadIdx.x;
    for (int i = t; i < NB; i += 256) h[i] = 0;
    __syncthreads();
    int base = blockIdx.x * TILE_E;
    #pragma unroll
    for (int k = 0; k < 16; k++) {
        int e = base + k * 256 + t;
        if (e < EE) {
            atomicAdd(&h[hidx[e] >> 6], 1);
            atomicAdd(&h[391 + (nidx[e] >> 8)], 1);
        }
    }
    __syncthreads();
    for (int i = t; i < NB; i += 256) counts[blockIdx.x * NB + i] = h[i];
}

// ---------------- pass A2: column-scan counts (in place -> per-block prior) + bucket bases ------
__global__ __launch_bounds__(1024) void k_scanA(int* __restrict__ counts, int* __restrict__ bbase) {
    __shared__ int tot[1024];
    int t = threadIdx.x;
    int run = 0;
    if (t < NB) {
        for (int b = 0; b < GA; b++) {
            int c = counts[b * NB + t];
            counts[b * NB + t] = run;
            run += c;
        }
    }
    tot[t] = (t < NB) ? run : 0;
    __syncthreads();
    for (int o = 1; o < 1024; o <<= 1) {
        int v = (t >= o) ? tot[t - o] : 0;
        __syncthreads();
        tot[t] += v;
        __syncthreads();
    }
    if (t < NB) bbase[t] = tot[t] - run;          // exclusive
    if (t == NB - 1) bbase[NB] = tot[t];          // total = 2*EE
}

// ---------------- pass A3: scatter packed items into bucket runs ----------------
// he item: ((h&63)<<17)|n  in buckets [0,391); nd item: ((n&255)<<15)|h in [391,782).
__global__ __launch_bounds__(256) void k_scatA(const int* __restrict__ nidx, const int* __restrict__ hidx,
                                               const int* __restrict__ counts, const int* __restrict__ bbase,
                                               unsigned int* __restrict__ items) {
    __shared__ int cur[NB];
    int t = threadIdx.x;
    for (int i = t; i < NB; i += 256) cur[i] = bbase[i] + counts[blockIdx.x * NB + i];
    __syncthreads();
    int base = blockIdx.x * TILE_E;
    #pragma unroll
    for (int k = 0; k < 16; k++) {
        int e = base + k * 256 + t;
        if (e < EE) {
            int hh = hidx[e], nn = nidx[e];
            int p1 = atomicAdd(&cur[hh >> 6], 1);
            items[p1] = ((unsigned)(hh & 63) << 17) | (unsigned)nn;
            int p2 = atomicAdd(&cur[391 + (nn >> 8)], 1);
            items[p2] = ((unsigned)(nn & 255) << 15) | (unsigned)hh;
        }
    }
}

// ---------------- pass B: per-bucket group-by-key; emit ptr, inv, grouped adj (in place) --------
__global__ __launch_bounds__(256) void k_passB(unsigned int* __restrict__ items,  // == adj, in place
                                               const int* __restrict__ bbase,
                                               int* __restrict__ ptr, float* __restrict__ inv) {
    __shared__ unsigned int led[3072];
    __shared__ unsigned int grp[3072];
    __shared__ int bins[256], cur[256], tmp[256];
    int b = blockIdx.x, t = threadIdx.x;
    int base = bbase[b], cnt = bbase[b + 1] - base;
    bool he = b < 391;
    int nbins = he ? 64 : 256;
    int keybase = he ? b * 64 : MM + (b - 391) * 256;
    int shift = he ? 17 : 15;
    unsigned int mask = he ? 0x1FFFFu : 0x7FFFu;
    int keylim = he ? MM : TT;

    for (int i = t; i < cnt; i += 256) led[i] = items[base + i];
    if (t < 256) bins[t] = 0;
    __syncthreads();
    for (int i = t; i < cnt; i += 256) atomicAdd(&bins[led[i] >> shift], 1);
    __syncthreads();
    int v = (t < nbins) ? bins[t] : 0;
    tmp[t] = v;
    __syncthreads();
    for (int o = 1; o < 256; o <<= 1) {
        int u = (t >= o) ? tmp[t - o] : 0;
        __syncthreads();
        tmp[t] += u;
        __syncthreads();
    }
    int excl = tmp[t] - v;
    if (t < nbins) {
        int g = keybase + t;
        if (g < keylim) {
            ptr[g] = base + excl;
            inv[g] = v ? 1.f / (float)v : 0.f;
        }
        cur[t] = excl;
    }
    __syncthreads();
    for (int i = t; i < cnt; i += 256) {
        unsigned int it = led[i];
        int p = atomicAdd(&cur[it >> shift], 1);
        grp[p] = it & mask;
    }
    __syncthreads();
    for (int i = t; i < cnt; i += 256) items[base + i] = grp[i];
    if (b == NB - 1 && t == 0) ptr[TT] = 2 * EE;
}

// ---------------- gather: quad-per-row, 4 loads in flight per quad ----------------
__device__ __forceinline__ void gather_row(const unsigned int* __restrict__ X,
                                           const int* __restrict__ adj,
                                           int beg, int end, int ql, float* a) {
    for (int j = beg; j < end; j += 4) {
        int c = end - j;
        int n0 = adj[j];
        int n1 = (c > 1) ? adj[j + 1] : 0;
        int n2 = (c > 2) ? adj[j + 2] : 0;
        int n3 = (c > 3) ? adj[j + 3] : 0;
        uint4 v0 = *((const uint4*)(X + (unsigned)n0 * 64u) + ql);
        uint4 z = make_uint4(0u, 0u, 0u, 0u);
        uint4 v1 = z, v2 = z, v3 = z;
        if (c > 1) v1 = *((const uint4*)(X + (unsigned)n1 * 64u) + ql);
        if (c > 2) v2 = *((const uint4*)(X + (unsigned)n2 * 64u) + ql);
        if (c > 3) v3 = *((const uint4*)(X + (unsigned)n3 * 64u) + ql);
        acc8(a, v0); acc8(a, v1); acc8(a, v2); acc8(a, v3);
    }
}

// hyperedge side: s_e = b_inv * sum x[node]
__global__ __launch_bounds__(256) void k_gather_he(const unsigned int* __restrict__ X,
        const int* __restrict__ ptr, const int* __restrict__ adj,
        const float* __restrict__ b_inv, unsigned int* __restrict__ s) {
    int gw = (blockIdx.x * 256 + threadIdx.x) >> 6;
    int lane = threadIdx.x & 63, quad = lane >> 4, ql = lane & 15;
    int r = gw * 4 + quad;
    if (r >= MM) return;
    int beg = ptr[r], end = ptr[r + 1];
    float a[8] = {0.f,0.f,0.f,0.f,0.f,0.f,0.f,0.f};
    gather_row(X, adj, beg, end, ql, a);
    float sc = b_inv[r];
    uint4 o;
    o.x = packbf2(a[0] * sc, a[1] * sc);
    o.y = packbf2(a[2] * sc, a[3] * sc);
    o.z = packbf2(a[4] * sc, a[5] * sc);
    o.w = packbf2(a[6] * sc, a[7] * sc);
    ((uint4*)(s + (unsigned)r * 64u))[ql] = o;
}

// node side: out = elu(d_inv * sum m[e] + b)
template<bool F32OUT>
__global__ __launch_bounds__(256) void k_gather_nd(const unsigned int* __restrict__ X,
        const int* __restrict__ ptr, const int* __restrict__ adj,
        const float* __restrict__ d_inv, const float* __restrict__ bias, void* __restrict__ out) {
    int gw = (blockIdx.x * 256 + threadIdx.x) >> 6;
    int lane = threadIdx.x & 63, quad = lane >> 4, ql = lane & 15;
    int r = gw * 4 + quad;
    if (r >= NN) return;
    int beg = ptr[r], end = ptr[r + 1];
    float a[8] = {0.f,0.f,0.f,0.f,0.f,0.f,0.f,0.f};
    gather_row(X, adj, beg, end, ql, a);
    float sc = d_inv[r];
    const float4* b4 = (const float4*)bias;
    float4 bA = b4[ql * 2], bB = b4[ql * 2 + 1];
    float f[8];
    f[0] = a[0] * sc + bA.x; f[1] = a[1] * sc + bA.y;
    f[2] = a[2] * sc + bA.z; f[3] = a[3] * sc + bA.w;
    f[4] = a[4] * sc + bB.x; f[5] = a[5] * sc + bB.y;
    f[6] = a[6] * sc + bB.z; f[7] = a[7] * sc + bB.w;
    #pragma unroll
    for (int i = 0; i < 8; i++) f[i] = f[i] > 0.f ? f[i] : __expf(f[i]) - 1.f;
    if (F32OUT) {
        float* o = (float*)out + (unsigned)r * 128u;
        ((float4*)o)[ql * 2]     = make_float4(f[0], f[1], f[2], f[3]);
        ((float4*)o)[ql * 2 + 1] = make_float4(f[4], f[5], f[6], f[7]);
    } else {
        uint4 o4;
        o4.x = packbf2(f[0], f[1]); o4.y = packbf2(f[2], f[3]);
        o4.z = packbf2(f[4], f[5]); o4.w = packbf2(f[6], f[7]);
        ((uint4*)((unsigned int*)out + (unsigned)r * 64u))[ql] = o4;
    }
}

// ---------------- GEMM  m[MM,128] = s[MM,128] @ W  (WT is W^T, bf16) ----------------
__global__ __launch_bounds__(256) void k_gemm(const unsigned short* __restrict__ A,
                                              const unsigned short* __restrict__ WT,
                                              unsigned short* __restrict__ C) {
    int lane = threadIdx.x & 63;
    int wv = threadIdx.x >> 6;
    int r0 = blockIdx.x * 64 + wv * 16;
    int mm = lane & 15;
    int quad = lane >> 4;
    floatx4 acc[8];
    #pragma unroll
    for (int c = 0; c < 8; c++) acc[c] = (floatx4){0.f, 0.f, 0.f, 0.f};
    int arow = r0 + mm; if (arow >= MM) arow = MM - 1;
    #pragma unroll
    for (int q = 0; q < 4; q++) {
        short8 af = *reinterpret_cast<const short8*>(A + arow * 128 + q * 32 + quad * 8);
        #pragma unroll
        for (int c = 0; c < 8; c++) {
            short8 bf = *reinterpret_cast<const short8*>(WT + (c * 16 + mm) * 128 + q * 32 + quad * 8);
            acc[c] = __builtin_amdgcn_mfma_f32_16x16x32_bf16(af, bf, acc[c], 0, 0, 0);
        }
    }
    #pragma unroll
    for (int c = 0; c < 8; c++) {
        #pragma unroll
        for (int r = 0; r < 4; r++) {
            int row = r0 + quad * 4 + r;
            if (row < MM) C[row * 128 + c * 16 + mm] = f2bf(acc[c][r]);
        }
    }
}

extern "C" void kernel_launch(void* const* d_in, const int* in_sizes, int n_in,
                              void* d_out, int out_size, void* d_ws, size_t ws_size,
                              hipStream_t stream) {
    const float* x  = (const float*)d_in[0];
    const float* W1 = (const float*)d_in[1];
    const float* b1 = (const float*)d_in[2];
    const float* W2 = (const float*)d_in[3];
    const float* b2 = (const float*)d_in[4];
    const float* W3 = (const float*)d_in[5];
    const float* b3 = (const float*)d_in[6];
    const int* nidx = (const int*)d_in[7];
    const int* hidx = (const int*)d_in[8];

    char* ws = (char*)d_ws;
    size_t o = 0;
    auto alloc = [&](size_t b) -> char* { char* p = ws + o; o = (o + b + 255) & ~(size_t)255; return p; };
    int*   ptr    = (int*)alloc((TT + 1) * 4);
    float* invq   = (float*)alloc(TT * 4);               // [0,MM): b_inv ; [MM,TT): d_inv
    int*   counts = (int*)alloc((size_t)GA * NB * 4);
    int*   bbase  = (int*)alloc((NB + 1) * 4);
    int*   adj    = (int*)alloc((size_t)2 * EE * 4);     // packed items -> grouped payloads (in place)
    unsigned short* WT   = (unsigned short*)alloc(3 * 128 * 128 * 2);
    unsigned short* sbuf = (unsigned short*)alloc((size_t)MM * 128 * 2);
    unsigned short* mbuf = (unsigned short*)alloc((size_t)MM * 128 * 2);

    // d_out hosts: xb/bufA (first half), bufB (second half), final f32 (all)
    unsigned int* xb   = (unsigned int*)d_out;
    unsigned int* bufA = (unsigned int*)d_out;
    unsigned int* bufB = (unsigned int*)d_out + (size_t)NN * 64;

    k_setup<<<CVT_BLOCKS + 3, 256, 0, stream>>>(x, xb, W1, W2, W3, WT);
    k_histA<<<GA, 256, 0, stream>>>(nidx, hidx, counts);
    k_scanA<<<1, 1024, 0, stream>>>(counts, bbase);
    k_scatA<<<GA, 256, 0, stream>>>(nidx, hidx, counts, bbase, (unsigned int*)adj);
    k_passB<<<NB, 256, 0, stream>>>((unsigned int*)adj, bbase, ptr, invq);

    const float* b_inv = invq;
    const float* d_inv = invq + MM;
    const int* nptr = ptr + MM;
    const int* nadj = adj;                 // nd payload region is [EE,2EE); nptr offsets already point there
    const int grid_he = (MM / 4 * 64 + 255) / 256;   // 1563
    const int grid_nd = (NN / 4 * 64 + 255) / 256;   // 6250
    const int grid_gm = (MM + 63) / 64;

    // Layer 0
    k_gather_he<<<grid_he, 256, 0, stream>>>(xb, ptr, adj, b_inv, (unsigned int*)sbuf);
    k_gemm<<<grid_gm, 256, 0, stream>>>(sbuf, WT, mbuf);
    k_gather_nd<false><<<grid_nd, 256, 0, stream>>>((const unsigned int*)mbuf, nptr, nadj, d_inv, b1, (void*)bufA);
    // Layer 1
    k_gather_he<<<grid_he, 256, 0, stream>>>(bufA, ptr, adj, b_inv, (unsigned int*)sbuf);
    k_gemm<<<grid_gm, 256, 0, stream>>>(sbuf, WT + 16384, mbuf);
    k_gather_nd<false><<<grid_nd, 256, 0, stream>>>((const unsigned int*)mbuf, nptr, nadj, d_inv, b2, (void*)bufB);
    // Layer 2
    k_gather_he<<<grid_he, 256, 0, stream>>>(bufB, ptr, adj, b_inv, (unsigned int*)sbuf);
    k_gemm<<<grid_gm, 256, 0, stream>>>(sbuf, WT + 32768, mbuf);
    k_gather_nd<true ><<<grid_nd, 256, 0, stream>>>((const unsigned int*)mbuf, nptr, nadj, d_inv, b3, d_out);
}

// Round 6
// 362.187 us; speedup vs baseline: 1.6158x; 1.0075x over previous
//
#include <hip/hip_runtime.h>

#define NN 100000
#define MM 25000
#define EE 600000
#define TT (MM + NN)

#define CVT_BLOCKS 12500              // NN*128/4/256 exact
#define NB 782                        // 391 he buckets (h>>6) + 391 nd buckets (n>>8)
#define CAP 2048                      // bucket capacity (expected 1536, sigma ~39)
#define TILE_E 4096
#define GA ((EE + TILE_E - 1) / TILE_E)   // 147

typedef __attribute__((ext_vector_type(8))) short short8;
typedef __attribute__((ext_vector_type(4))) float floatx4;

__device__ __forceinline__ float bl(unsigned int u){ return __uint_as_float(u << 16); }
__device__ __forceinline__ float bh(unsigned int u){ return __uint_as_float(u & 0xffff0000u); }
__device__ __forceinline__ unsigned int packbf2(float a, float b){
    unsigned int ua = __float_as_uint(a), ub = __float_as_uint(b);
    ua = (ua + 0x7fffu + ((ua >> 16) & 1u)) >> 16;
    ub = (ub + 0x7fffu + ((ub >> 16) & 1u)) & 0xffff0000u;
    return ua | ub;
}
__device__ __forceinline__ unsigned short f2bf(float f){
    unsigned int u = __float_as_uint(f);
    return (unsigned short)((u + 0x7fffu + ((u >> 16) & 1u)) >> 16);
}
__device__ __forceinline__ void acc8(float* a, uint4 v){
    a[0] += bl(v.x); a[1] += bh(v.x);
    a[2] += bl(v.y); a[3] += bh(v.y);
    a[4] += bl(v.z); a[5] += bh(v.z);
    a[6] += bl(v.w); a[7] += bh(v.w);
}

// ---------------- preamble: x->bf16 | weight transpose | bucket-cursor init ----------------
__global__ void k_setup(const float* __restrict__ x, unsigned int* __restrict__ xb,
                        const float* __restrict__ W1, const float* __restrict__ W2,
                        const float* __restrict__ W3, unsigned short* __restrict__ WT,
                        int* __restrict__ gcur) {
    int b = blockIdx.x;
    if (b < CVT_BLOCKS) {
        int t = b * 256 + threadIdx.x;
        float4 v = ((const float4*)x)[t];
        uint2 o; o.x = packbf2(v.x, v.y); o.y = packbf2(v.z, v.w);
        ((uint2*)xb)[t] = o;
    } else if (b < CVT_BLOCKS + 3) {
        int l = b - CVT_BLOCKS;
        const float* W = l == 0 ? W1 : (l == 1 ? W2 : W3);
        unsigned short* T = WT + l * 16384;
        for (int i = threadIdx.x; i < 16384; i += 256) {
            int k = i >> 7, c = i & 127;
            T[c * 128 + k] = f2bf(W[k * 128 + c]);
        }
    } else {
        for (int i = threadIdx.x; i < NB; i += 256) gcur[i] = i * CAP;
    }
}

// ---------------- CSR build pass A: LDS hist -> reserve -> scatter into padded buckets --------
// he item: ((h&63)<<17)|n  in buckets [0,391); nd item: ((n&255)<<15)|h in [391,782).
__global__ __launch_bounds__(256) void k_binA(const int* __restrict__ nidx, const int* __restrict__ hidx,
                                              int* __restrict__ gcur, unsigned int* __restrict__ items) {
    __shared__ int h[NB];
    __shared__ int cur[NB];
    int t = threadIdx.x;
    for (int i = t; i < NB; i += 256) h[i] = 0;
    __syncthreads();
    int base = blockIdx.x * TILE_E;
    #pragma unroll
    for (int k = 0; k < 16; k++) {
        int e = base + k * 256 + t;
        if (e < EE) {
            atomicAdd(&h[hidx[e] >> 6], 1);
            atomicAdd(&h[391 + (nidx[e] >> 8)], 1);
        }
    }
    __syncthreads();
    for (int i = t; i < NB; i += 256) {
        int c = h[i];
        cur[i] = c ? atomicAdd(&gcur[i], c) : 0;
    }
    __syncthreads();
    #pragma unroll
    for (int k = 0; k < 16; k++) {
        int e = base + k * 256 + t;
        if (e < EE) {
            int hh = hidx[e], nn = nidx[e];
            int p1 = atomicAdd(&cur[hh >> 6], 1);
            items[p1] = ((unsigned)(hh & 63) << 17) | (unsigned)nn;
            int p2 = atomicAdd(&cur[391 + (nn >> 8)], 1);
            items[p2] = ((unsigned)(nn & 255) << 15) | (unsigned)hh;
        }
    }
}

// ---------------- pass B: per-bucket group-by-key; emit ptr2{beg,deg}, inv, grouped adj --------
__global__ __launch_bounds__(256) void k_passB(unsigned int* __restrict__ items,  // adj, in place
                                               const int* __restrict__ gcur,
                                               int2* __restrict__ ptr2, float* __restrict__ inv) {
    __shared__ unsigned int led[CAP];
    __shared__ unsigned int grp[CAP];
    __shared__ int bins[256], cur[256], tmp[256];
    int b = blockIdx.x, t = threadIdx.x;
    int base = b * CAP, cnt = gcur[b] - base;
    bool he = b < 391;
    int nbins = he ? 64 : 256;
    int keybase = he ? b * 64 : MM + (b - 391) * 256;
    int shift = he ? 17 : 15;
    unsigned int mask = he ? 0x1FFFFu : 0x7FFFu;
    int keylim = he ? MM : TT;

    for (int i = t; i < cnt; i += 256) led[i] = items[base + i];
    bins[t] = 0;
    __syncthreads();
    for (int i = t; i < cnt; i += 256) atomicAdd(&bins[led[i] >> shift], 1);
    __syncthreads();
    int v = (t < nbins) ? bins[t] : 0;
    tmp[t] = v;
    __syncthreads();
    for (int o = 1; o < 256; o <<= 1) {
        int u = (t >= o) ? tmp[t - o] : 0;
        __syncthreads();
        tmp[t] += u;
        __syncthreads();
    }
    int excl = tmp[t] - v;
    if (t < nbins) {
        int g = keybase + t;
        if (g < keylim) {
            ptr2[g] = make_int2(base + excl, v);
            inv[g] = v ? 1.f / (float)v : 0.f;
        }
        cur[t] = excl;
    }
    __syncthreads();
    for (int i = t; i < cnt; i += 256) {
        unsigned int it = led[i];
        int p = atomicAdd(&cur[it >> shift], 1);
        grp[p] = it & mask;
    }
    __syncthreads();
    for (int i = t; i < cnt; i += 256) items[base + i] = grp[i];
}

// ---------------- gather core: quad-per-row, 8 loads in flight ----------------
__device__ __forceinline__ void gather_row8(const unsigned int* __restrict__ X,
                                            const unsigned int* __restrict__ adj,
                                            int beg, int deg, int ql, float* a) {
    int end = beg + deg;
    for (int j = beg; j < end; j += 8) {
        int c = end - j;
        int n[8];
        #pragma unroll
        for (int i = 0; i < 8; i++) n[i] = (i < c) ? (int)adj[j + i] : 0;
        uint4 z = make_uint4(0u, 0u, 0u, 0u);
        uint4 v[8];
        #pragma unroll
        for (int i = 0; i < 8; i++) {
            v[i] = z;
            if (i < c) v[i] = *((const uint4*)(X + (unsigned)n[i] * 64u) + ql);
        }
        #pragma unroll
        for (int i = 0; i < 8; i++) acc8(a, v[i]);
    }
}

// ---------------- fused hyperedge gather + GEMM:  m = (b_inv * sum x) @ W ----------------
// block = 16 rows; quad q gathers row r0+q into LDS bf16 tile; 4 waves each do 2 col-blocks.
__global__ __launch_bounds__(256) void k_hegemm(const unsigned int* __restrict__ X,
        const int2* __restrict__ ptr2, const unsigned int* __restrict__ adj,
        const float* __restrict__ b_inv, const unsigned short* __restrict__ WT,
        unsigned short* __restrict__ C) {
    __shared__ unsigned int tile[16 * 68];        // 16 rows x 128 bf16, +16B row pad
    int t = threadIdx.x;
    int qidx = t >> 4, ql = t & 15;
    int r0 = blockIdx.x * 16;
    int r = r0 + qidx;
    float a[8] = {0.f,0.f,0.f,0.f,0.f,0.f,0.f,0.f};
    float sc = 0.f;
    if (r < MM) {
        int2 pe = ptr2[r];
        gather_row8(X, adj, pe.x, pe.y, ql, a);
        sc = b_inv[r];
    }
    uint4 o;
    o.x = packbf2(a[0] * sc, a[1] * sc);
    o.y = packbf2(a[2] * sc, a[3] * sc);
    o.z = packbf2(a[4] * sc, a[5] * sc);
    o.w = packbf2(a[6] * sc, a[7] * sc);
    *((uint4*)(tile + qidx * 68 + ql * 4)) = o;
    __syncthreads();

    int wv = t >> 6, lane = t & 63;
    int mm = lane & 15, quad = lane >> 4;
    floatx4 acc0 = (floatx4){0.f,0.f,0.f,0.f}, acc1 = acc0;
    int c0 = wv * 2;
    #pragma unroll
    for (int q = 0; q < 4; q++) {
        short8 af = *reinterpret_cast<const short8*>((const short*)(tile + mm * 68) + q * 32 + quad * 8);
        short8 b0 = *reinterpret_cast<const short8*>(WT + (c0 * 16 + mm) * 128 + q * 32 + quad * 8);
        short8 b1 = *reinterpret_cast<const short8*>(WT + ((c0 + 1) * 16 + mm) * 128 + q * 32 + quad * 8);
        acc0 = __builtin_amdgcn_mfma_f32_16x16x32_bf16(af, b0, acc0, 0, 0, 0);
        acc1 = __builtin_amdgcn_mfma_f32_16x16x32_bf16(af, b1, acc1, 0, 0, 0);
    }
    #pragma unroll
    for (int rg = 0; rg < 4; rg++) {
        int rr = r0 + quad * 4 + rg;
        if (rr < MM) {
            C[rr * 128 + c0 * 16 + mm]       = f2bf(acc0[rg]);
            C[rr * 128 + (c0 + 1) * 16 + mm] = f2bf(acc1[rg]);
        }
    }
}

// ---------------- gather: node side  out = elu(d_inv * sum m[e] + b) ----------------
template<bool F32OUT>
__global__ __launch_bounds__(256) void k_gather_nd(const unsigned int* __restrict__ X,
        const int2* __restrict__ ptr2, const unsigned int* __restrict__ adj,
        const float* __restrict__ d_inv, const float* __restrict__ bias, void* __restrict__ out) {
    int gw = (blockIdx.x * 256 + threadIdx.x) >> 6;
    int lane = threadIdx.x & 63, quad = lane >> 4, ql = lane & 15;
    int r = gw * 4 + quad;
    if (r >= NN) return;
    int2 pe = ptr2[r];
    float a[8] = {0.f,0.f,0.f,0.f,0.f,0.f,0.f,0.f};
    gather_row8(X, adj, pe.x, pe.y, ql, a);
    float sc = d_inv[r];
    const float4* b4 = (const float4*)bias;
    float4 bA = b4[ql * 2], bB = b4[ql * 2 + 1];
    float f[8];
    f[0] = a[0] * sc + bA.x; f[1] = a[1] * sc + bA.y;
    f[2] = a[2] * sc + bA.z; f[3] = a[3] * sc + bA.w;
    f[4] = a[4] * sc + bB.x; f[5] = a[5] * sc + bB.y;
    f[6] = a[6] * sc + bB.z; f[7] = a[7] * sc + bB.w;
    #pragma unroll
    for (int i = 0; i < 8; i++) f[i] = f[i] > 0.f ? f[i] : __expf(f[i]) - 1.f;
    if (F32OUT) {
        float* o = (float*)out + (unsigned)r * 128u;
        ((float4*)o)[ql * 2]     = make_float4(f[0], f[1], f[2], f[3]);
        ((float4*)o)[ql * 2 + 1] = make_float4(f[4], f[5], f[6], f[7]);
    } else {
        uint4 o4;
        o4.x = packbf2(f[0], f[1]); o4.y = packbf2(f[2], f[3]);
        o4.z = packbf2(f[4], f[5]); o4.w = packbf2(f[6], f[7]);
        ((uint4*)((unsigned int*)out + (unsigned)r * 64u))[ql] = o4;
    }
}

extern "C" void kernel_launch(void* const* d_in, const int* in_sizes, int n_in,
                              void* d_out, int out_size, void* d_ws, size_t ws_size,
                              hipStream_t stream) {
    const float* x  = (const float*)d_in[0];
    const float* W1 = (const float*)d_in[1];
    const float* b1 = (const float*)d_in[2];
    const float* W2 = (const float*)d_in[3];
    const float* b2 = (const float*)d_in[4];
    const float* W3 = (const float*)d_in[5];
    const float* b3 = (const float*)d_in[6];
    const int* nidx = (const int*)d_in[7];
    const int* hidx = (const int*)d_in[8];

    char* ws = (char*)d_ws;
    size_t o = 0;
    auto alloc = [&](size_t b) -> char* { char* p = ws + o; o = (o + b + 255) & ~(size_t)255; return p; };
    int2*  ptr2  = (int2*)alloc((size_t)TT * 8);
    float* invq  = (float*)alloc(TT * 4);                  // [0,MM): b_inv ; [MM,TT): d_inv
    int*   gcur  = (int*)alloc(NB * 4);
    unsigned int* items = (unsigned int*)alloc((size_t)NB * CAP * 4);  // padded buckets -> grouped adj
    unsigned short* WT   = (unsigned short*)alloc(3 * 128 * 128 * 2);
    unsigned short* mbuf = (unsigned short*)alloc((size_t)MM * 128 * 2);

    // d_out hosts: xb/bufA (first half), bufB (second half), final f32 (all)
    unsigned int* xb   = (unsigned int*)d_out;
    unsigned int* bufA = (unsigned int*)d_out;
    unsigned int* bufB = (unsigned int*)d_out + (size_t)NN * 64;

    k_setup<<<CVT_BLOCKS + 4, 256, 0, stream>>>(x, xb, W1, W2, W3, WT, gcur);
    k_binA<<<GA, 256, 0, stream>>>(nidx, hidx, gcur, items);
    k_passB<<<NB, 256, 0, stream>>>(items, gcur, ptr2, invq);

    const float* b_inv = invq;
    const float* d_inv = invq + MM;
    const int2* nptr2 = ptr2 + MM;
    const int grid_hg = (MM + 15) / 16;              // 1563
    const int grid_nd = NN * 64 / 256;               // 25000 rows /4 per wave -> 6250 blocks
    const unsigned int* adj = items;

    // Layer 0
    k_hegemm<<<grid_hg, 256, 0, stream>>>(xb, ptr2, adj, b_inv, WT, mbuf);
    k_gather_nd<false><<<grid_nd, 256, 0, stream>>>((const unsigned int*)mbuf, nptr2, adj, d_inv, b1, (void*)bufA);
    // Layer 1
    k_hegemm<<<grid_hg, 256, 0, stream>>>(bufA, ptr2, adj, b_inv, WT + 16384, mbuf);
    k_gather_nd<false><<<grid_nd, 256, 0, stream>>>((const unsigned int*)mbuf, nptr2, adj, d_inv, b2, (void*)bufB);
    // Layer 2
    k_hegemm<<<grid_hg, 256, 0, stream>>>(bufB, ptr2, adj, b_inv, WT + 32768, mbuf);
    k_gather_nd<true ><<<grid_nd, 256, 0, stream>>>((const unsigned int*)mbuf, nptr2, adj, d_inv, b3, d_out);
}